// Round 9
// baseline (112.943 us; speedup 1.0000x reference)
//
#include <hip/hip_runtime.h>
#include <cstdint>
#include <cstddef>

#define PP 64
#define KK 8
#define HH 32
#define DD 2048
#define RR (PP*HH)        // 2048 center rows

typedef __attribute__((ext_vector_type(4))) float  f32x4;
typedef __attribute__((ext_vector_type(4))) float  float4v;
typedef __attribute__((ext_vector_type(8))) __bf16 bf16x8;

__device__ __forceinline__ unsigned short f2bf(float f) {
  unsigned int u = __builtin_bit_cast(unsigned int, f);
  u += 0x7fffu + ((u >> 16) & 1u);
  return (unsigned short)(u >> 16);
}

__device__ __forceinline__ void gload_lds16(const void* g, void* l) {
  __builtin_amdgcn_global_load_lds(
      (const __attribute__((address_space(1))) void*)g,
      (__attribute__((address_space(3))) void*)l, 16, 0, 0);
}

// Proven 63-step anti-diagonal wavefront DP over a 32x32 tile (lanes 0..31 active).
__device__ __forceinline__ float dp_wave(const float* tile, int j32, int stride) {
  const float INF = __builtin_inff();
  float A = INF;
  for (int d = 0; d < 63; ++d) {
    float left = __shfl_up(A, 1, 32);
    if (j32 == 0) left = INF;
    int i = d - j32;
    int ii = i < 0 ? 0 : (i > 31 ? 31 : i);
    float dv = tile[ii*stride + j32];
    float up = (i == 0) ? (j32 == 0 ? 0.f : INF) : A;
    A = (i >= 0 && i < 32) ? (fminf(up, left) + dv) : INF;
  }
  return A;  // valid at j32 == 31
}

// K1: centers (mean over K), bf16 centers, bf16 feature copy, row norms. (R5/R7-proven)
__global__ __launch_bounds__(256) void k_centers(const float* __restrict__ feat,
    unsigned short* __restrict__ cbf, unsigned short* __restrict__ fbf,
    float* __restrict__ cnorm, float* __restrict__ fnorm) {
  int row = blockIdx.x;            // p*32 + h
  int p = row >> 5, h = row & 31;
  int tid = threadIdx.x;
  int d0 = tid * 8;
  float c[8];
  float red[9];
  #pragma unroll
  for (int e = 0; e < 8; ++e) c[e] = 0.f;
  #pragma unroll
  for (int k = 0; k < KK; ++k) {
    size_t frow = (size_t)((p*KK + k)*HH + h);
    const float* src = feat + frow*DD + d0;
    float4v f0 = *(const float4v*)src;
    float4v f1 = *(const float4v*)(src + 4);
    float s = 0.f;
    #pragma unroll
    for (int e = 0; e < 4; ++e) {
      c[e]   += f0[e];
      c[4+e] += f1[e];
      s += f0[e]*f0[e] + f1[e]*f1[e];
    }
    red[k] = s;
    unsigned int fk[4];
    #pragma unroll
    for (int e = 0; e < 2; ++e) {
      fk[e]   = (unsigned int)f2bf(f0[2*e]) | ((unsigned int)f2bf(f0[2*e+1]) << 16);
      fk[2+e] = (unsigned int)f2bf(f1[2*e]) | ((unsigned int)f2bf(f1[2*e+1]) << 16);
    }
    *(uint4*)(fbf + frow*DD + d0) = make_uint4(fk[0], fk[1], fk[2], fk[3]);
  }
  float csq = 0.f;
  #pragma unroll
  for (int e = 0; e < 8; ++e) { c[e] *= 0.125f; csq += c[e]*c[e]; }
  unsigned int pk[4];
  #pragma unroll
  for (int e = 0; e < 4; ++e)
    pk[e] = (unsigned int)f2bf(c[2*e]) | ((unsigned int)f2bf(c[2*e+1]) << 16);
  *(uint4*)(cbf + (size_t)row*DD + d0) = make_uint4(pk[0], pk[1], pk[2], pk[3]);
  red[8] = csq;

  __shared__ float lred[4][9];
  int lane = tid & 63, wv = tid >> 6;
  #pragma unroll
  for (int r = 0; r < 9; ++r) {
    float v = red[r];
    #pragma unroll
    for (int off = 32; off > 0; off >>= 1) v += __shfl_down(v, off, 64);
    if (lane == 0) lred[wv][r] = v;
  }
  __syncthreads();
  if (tid < 9) {
    float s = lred[0][tid] + lred[1][tid] + lred[2][tid] + lred[3][tid];
    if (tid < 8) fnorm[((size_t)(p*KK + tid))*HH + h] = s;
    else         cnorm[row] = s;
  }
}

// K2: merged Gram + fused DP.
// Blocks 0..135  : inter, 128x128 tiles over 16x16 tile grid (upper-tri, 136 = 8*17
//                  XCD-swizzled), 4 waves (2x2 quadrants), acc[4][4], BK=32,
//                  3-buffer depth-2 counted-vmcnt pipeline; per-wave DP over its
//                  4 pairs -> inter_full (+mirror).
// Blocks 136..647: intra (class p, block jb; bf16 fbf source; R8-proven path).
__global__ __launch_bounds__(256) void k_gram(const unsigned short* __restrict__ cbf,
    const unsigned short* __restrict__ fbf, const float* __restrict__ cnorm,
    const float* __restrict__ fnorm, float* __restrict__ inter_full,
    float* __restrict__ intra_pk) {
  __shared__ char smem[49152];   // inter: 3 x 16 KB; intra: 3 x 8 KB + epilogue
  int tid = threadIdx.x, lane = tid & 63, w = tid >> 6;
  int ln = lane & 15, kq = lane >> 4;

  if (blockIdx.x < 136) {
    // ---------------- inter path: 128x128 tile ----------------
    int bid = (blockIdx.x & 7)*17 + (blockIdx.x >> 3);      // 136 = 8*17, bijective
    int tI = 0, rem = bid;
    while (rem >= 16 - tI) { rem -= 16 - tI; ++tI; }
    int tJ = tI + rem;
    int wr = w >> 1, wc = w & 1;
    f32x4 acc[4][4];
    #pragma unroll
    for (int a = 0; a < 4; ++a)
      #pragma unroll
      for (int b = 0; b < 4; ++b)
        #pragma unroll
        for (int e = 0; e < 4; ++e) acc[a][b][e] = 0.f;

    // staging: per K-step wave w stages A rows [w*32, w*32+32) x 32K (2 gloads) + B same.
    // LDS layout [128][32] bf16 per panel, phys chunk = logchunk ^ ((row>>1)&3).
    // For staging, (row>>1)&3 == (lane>>3)&3, so pre-swizzled global chunk is lane-only:
    int cch = (lane & 3) ^ ((lane >> 3) & 3);
    int rA = w*32 + (lane >> 2);                            // +q*16
    const unsigned short* gA0 = cbf + (size_t)(tI*128 + rA)*DD + cch*8;
    const unsigned short* gB0 = cbf + (size_t)(tJ*128 + rA)*DD + cch*8;

    auto stage = [&](int tt, int bi) {
      int k0 = tt * 32;
      char* A = smem + bi*16384;
      char* B = A + 8192;
      gload_lds16(gA0 + k0,         A + w*2048 + lane*16);
      gload_lds16(gA0 + 16*DD + k0, A + w*2048 + 1024 + lane*16);
      gload_lds16(gB0 + k0,         B + w*2048 + lane*16);
      gload_lds16(gB0 + 16*DD + k0, B + w*2048 + 1024 + lane*16);
    };

    // fragment byte offsets: row*64 + (kq ^ ((ln>>1)&3))*16  (row>>1&3 == ln>>1&3 here)
    int physb = (kq ^ ((ln >> 1) & 3)) * 16;
    int aofs[4], bofs[4];
    #pragma unroll
    for (int mt = 0; mt < 4; ++mt) {
      aofs[mt] = (wr*64 + mt*16 + ln)*64 + physb;
      bofs[mt] = (wc*64 + mt*16 + ln)*64 + physb;
    }

    auto do_step = [&](int bi) {
      const char* A = smem + bi*16384;
      const char* B = A + 8192;
      bf16x8 af[4], bfr[4];
      #pragma unroll
      for (int mt = 0; mt < 4; ++mt) {
        af[mt]  = *(const bf16x8*)(A + aofs[mt]);
        bfr[mt] = *(const bf16x8*)(B + bofs[mt]);
      }
      #pragma unroll
      for (int mt = 0; mt < 4; ++mt)
        #pragma unroll
        for (int nt = 0; nt < 4; ++nt)
          acc[mt][nt] = __builtin_amdgcn_mfma_f32_16x16x32_bf16(af[mt], bfr[nt], acc[mt][nt], 0, 0, 0);
    };

    stage(0, 0);
    stage(1, 1);
    asm volatile("s_waitcnt vmcnt(4)" ::: "memory");
    __builtin_amdgcn_s_barrier();
    for (int t = 0; t < 62; ++t) {
      stage(t + 2, (t + 2) % 3);
      do_step(t % 3);
      asm volatile("s_waitcnt vmcnt(4)" ::: "memory");
      __builtin_amdgcn_s_barrier();
    }
    do_step(2);                                           // t=62 (62%3==2)
    asm volatile("s_waitcnt vmcnt(0)" ::: "memory");
    __builtin_amdgcn_s_barrier();
    do_step(0);                                           // t=63 (63%3==0)
    __syncthreads();

    // epilogue: per wave, 2x2 pairs; tile stride 33 (conflict-free write+DP read)
    float* tile = (float*)(smem + w*4352);
    #pragma unroll
    for (int ia = 0; ia < 2; ++ia) {
      #pragma unroll
      for (int ib = 0; ib < 2; ++ib) {
        int a = tI*4 + wr*2 + ia;
        int b = tJ*4 + wc*2 + ib;
        if (a >= b) continue;                              // wave-uniform
        #pragma unroll
        for (int m2 = 0; m2 < 2; ++m2) {
          #pragma unroll
          for (int n2 = 0; n2 < 2; ++n2) {
            int mt = ia*2 + m2, nt = ib*2 + n2;
            int j  = n2*16 + ln;
            int cc = tJ*128 + wc*64 + nt*16 + ln;
            float nc = cnorm[cc];
            #pragma unroll
            for (int v = 0; v < 4; ++v) {
              int i  = m2*16 + kq*4 + v;
              int rr = tI*128 + wr*64 + mt*16 + kq*4 + v;
              float d2 = cnorm[rr] + nc - 2.f*acc[mt][nt][v];
              tile[i*33 + j] = tanhf(0.5f*sqrtf(fmaxf(d2, 1e-12f)));
            }
          }
        }
        asm volatile("s_waitcnt lgkmcnt(0)" ::: "memory");
        __builtin_amdgcn_sched_barrier(0);
        float A = dp_wave(tile, lane & 31, 33);
        if (lane == 31) {
          inter_full[a*64 + b] = A;
          inter_full[b*64 + a] = A;
        }
      }
    }
  } else {
    // ---------------- intra path (R8-proven) ----------------
    int bid = (int)blockIdx.x - 136;
    int p = bid >> 3, jb = bid & 7;
    int ks = w >> 1, nt = w & 1;
    f32x4 acc[2];
    #pragma unroll
    for (int mi = 0; mi < 2; ++mi)
      #pragma unroll
      for (int e = 0; e < 4; ++e) acc[mi][e] = 0.f;

    int sr = lane >> 3, sc = lane & 7;
    int jch0 = sc ^ sr;
    int hw = w & 1;
    const unsigned short* g0 = (w < 2)
        ? cbf + (size_t)(p*32 + hw*16 + sr)*DD + jch0*8
        : fbf + (size_t)(p*256 + jb*32 + hw*16 + sr)*DD + jch0*8;
    int lofs = hw*1024 + lane*8;
    int isB = (w >= 2);

    int phys = ((ks*4 + kq) ^ (ln & 7))*8;
    int aofs[2];
    #pragma unroll
    for (int mi = 0; mi < 2; ++mi) aofs[mi] = (mi*16 + ln)*64 + phys;
    int bofs = (nt*16 + ln)*64 + phys;

    auto stage = [&](int tt, int bi) {
      int k0 = tt * 64;
      unsigned short* S = (unsigned short*)(smem + bi*8192) + isB*2048;
      gload_lds16(g0 + k0,        S + lofs);
      gload_lds16(g0 + 8*DD + k0, S + lofs + 512);
    };
    auto do_step = [&](int bi) {
      const unsigned short* A16 = (const unsigned short*)(smem + bi*8192);
      const unsigned short* B16 = A16 + 2048;
      bf16x8 bfr = *(const bf16x8*)(B16 + bofs);
      #pragma unroll
      for (int mi = 0; mi < 2; ++mi) {
        bf16x8 af = *(const bf16x8*)(A16 + aofs[mi]);
        acc[mi] = __builtin_amdgcn_mfma_f32_16x16x32_bf16(af, bfr, acc[mi], 0, 0, 0);
      }
    };

    stage(0, 0);
    stage(1, 1);
    asm volatile("s_waitcnt vmcnt(2)" ::: "memory");
    __builtin_amdgcn_s_barrier();
    for (int t = 0; t < 30; ++t) {
      stage(t + 2, (t + 2) % 3);
      do_step(t % 3);
      asm volatile("s_waitcnt vmcnt(2)" ::: "memory");
      __builtin_amdgcn_s_barrier();
    }
    do_step(0);
    asm volatile("s_waitcnt vmcnt(0)" ::: "memory");
    __builtin_amdgcn_s_barrier();
    do_step(1);

    // K-split reduce: waves 2,3 (ks=1) -> waves 0,1 (ks=0), matched nt
    float* fb = (float*)smem;
    float* tile = (float*)(smem + 16384);   // 32x32 pair tile
    __syncthreads();
    if (w >= 2) {
      #pragma unroll
      for (int mi = 0; mi < 2; ++mi)
        *(f32x4*)(fb + ((w - 2)*2 + mi)*256 + lane*4) = acc[mi];
    }
    __syncthreads();
    if (w < 2) {
      #pragma unroll
      for (int mi = 0; mi < 2; ++mi)
        acc[mi] += *(const f32x4*)(fb + (w*2 + mi)*256 + lane*4);
      int cl = jb*32 + nt*16 + ln;
      float nf = fnorm[(size_t)p*256 + cl];
      #pragma unroll
      for (int mi = 0; mi < 2; ++mi) {
        #pragma unroll
        for (int v = 0; v < 4; ++v) {
          int i = mi*16 + kq*4 + v;
          float d2 = cnorm[p*32 + i] + nf - 2.f*acc[mi][v];
          tile[(i << 5) + (nt*16 + ln)] = tanhf(0.5f*sqrtf(fmaxf(d2, 1e-12f)));
        }
      }
    }
    __syncthreads();
    if (w == 0) {
      float A = dp_wave(tile, lane & 31, 32);
      if (lane == 31) intra_pk[p*8 + jb] = A;
    }
  }
}

// K3: reductions + loss. out = [loss, intra_max[64], inter_min[64]]
__global__ __launch_bounds__(64) void k_final(const float* __restrict__ inter_full,
    const float* __restrict__ intra_pk, float* __restrict__ out) {
  int p = threadIdx.x;
  const float INF = __builtin_inff();
  float mn = INF;
  #pragma unroll 8
  for (int b = 0; b < 64; ++b)
    if (b != p) mn = fminf(mn, inter_full[p*64 + b]);
  float mx = -INF;
  #pragma unroll
  for (int k = 0; k < 8; ++k) mx = fmaxf(mx, intra_pk[p*8 + k]);
  out[1 + p]  = mx;
  out[65 + p] = mn;
  float v = fmaxf(mx - mn + 10.0f, 0.0f);
  #pragma unroll
  for (int off = 32; off > 0; off >>= 1) v += __shfl_down(v, off, 64);
  if (p == 0) out[0] = v * (1.0f/64.0f);
}

extern "C" void kernel_launch(void* const* d_in, const int* in_sizes, int n_in,
                              void* d_out, int out_size, void* d_ws, size_t ws_size,
                              hipStream_t stream) {
  const float* feat = (const float*)d_in[0];
  float* out = (float*)d_out;
  char* w = (char*)d_ws;
  // workspace layout (bytes)
  unsigned short* cbf = (unsigned short*)w;                 // 8,388,608
  unsigned short* fbf = (unsigned short*)(w + 8388608);     // 67,108,864
  float* cnorm        = (float*)(w + 75497472);             // 8,192
  float* fnorm        = (float*)(w + 75505664);             // 65,536
  float* inter_full   = (float*)(w + 75571200);             // 16,384
  float* intra_pk     = (float*)(w + 75587584);             // 2,048
  // total ~75.6 MB

  k_centers<<<RR, 256, 0, stream>>>(feat, cbf, fbf, cnorm, fnorm);
  k_gram<<<648, 256, 0, stream>>>(cbf, fbf, cnorm, fnorm, inter_full, intra_pk);
  k_final<<<1, 64, 0, stream>>>(inter_full, intra_pk, out);
}

// Round 10
// 67.243 us; speedup vs baseline: 1.6796x; 1.6796x over previous
//
#include <hip/hip_runtime.h>
#include <hip/hip_fp8.h>
#include <cstdint>
#include <cstddef>

#define PP 64
#define KK 8
#define HH 32
#define DD 2048
#define RR (PP*HH)        // 2048 center rows

typedef __attribute__((ext_vector_type(4))) float  f32x4;
typedef __attribute__((ext_vector_type(4))) float  float4v;

__device__ __forceinline__ unsigned int f2fp8(float f) {
  return (unsigned int)__hip_fp8_e4m3(f).__x;   // OCP e4m3fn byte
}

__device__ __forceinline__ void gload_lds16(const void* g, void* l) {
  __builtin_amdgcn_global_load_lds(
      (const __attribute__((address_space(1))) void*)g,
      (__attribute__((address_space(3))) void*)l, 16, 0, 0);
}

// Proven 63-step anti-diagonal wavefront DP over a 32x32 tile (lanes 0..31 active).
__device__ __forceinline__ float dp_wave(const float* tile, int j32, int stride) {
  const float INF = __builtin_inff();
  float A = INF;
  for (int d = 0; d < 63; ++d) {
    float left = __shfl_up(A, 1, 32);
    if (j32 == 0) left = INF;
    int i = d - j32;
    int ii = i < 0 ? 0 : (i > 31 ? 31 : i);
    float dv = tile[ii*stride + j32];
    float up = (i == 0) ? (j32 == 0 ? 0.f : INF) : A;
    A = (i >= 0 && i < 32) ? (fminf(up, left) + dv) : INF;
  }
  return A;  // valid at j32 == 31
}

// K1: centers (mean over K), fp8 centers, fp8 feature copy, fp32 row norms.
__global__ __launch_bounds__(256) void k_centers(const float* __restrict__ feat,
    unsigned char* __restrict__ cbf, unsigned char* __restrict__ fbf,
    float* __restrict__ cnorm, float* __restrict__ fnorm) {
  int row = blockIdx.x;            // p*32 + h
  int p = row >> 5, h = row & 31;
  int tid = threadIdx.x;
  int d0 = tid * 8;
  float c[8];
  float red[9];
  #pragma unroll
  for (int e = 0; e < 8; ++e) c[e] = 0.f;
  #pragma unroll
  for (int k = 0; k < KK; ++k) {
    size_t frow = (size_t)((p*KK + k)*HH + h);
    const float* src = feat + frow*DD + d0;
    float4v f0 = *(const float4v*)src;
    float4v f1 = *(const float4v*)(src + 4);
    float s = 0.f;
    #pragma unroll
    for (int e = 0; e < 4; ++e) {
      c[e]   += f0[e];
      c[4+e] += f1[e];
      s += f0[e]*f0[e] + f1[e]*f1[e];
    }
    red[k] = s;
    unsigned int lo = f2fp8(f0[0]) | (f2fp8(f0[1])<<8) | (f2fp8(f0[2])<<16) | (f2fp8(f0[3])<<24);
    unsigned int hi = f2fp8(f1[0]) | (f2fp8(f1[1])<<8) | (f2fp8(f1[2])<<16) | (f2fp8(f1[3])<<24);
    *(uint2*)(fbf + frow*DD + d0) = make_uint2(lo, hi);
  }
  float csq = 0.f;
  #pragma unroll
  for (int e = 0; e < 8; ++e) { c[e] *= 0.125f; csq += c[e]*c[e]; }
  {
    unsigned int lo = f2fp8(c[0]) | (f2fp8(c[1])<<8) | (f2fp8(c[2])<<16) | (f2fp8(c[3])<<24);
    unsigned int hi = f2fp8(c[4]) | (f2fp8(c[5])<<8) | (f2fp8(c[6])<<16) | (f2fp8(c[7])<<24);
    *(uint2*)(cbf + (size_t)row*DD + d0) = make_uint2(lo, hi);
  }
  red[8] = csq;

  __shared__ float lred[4][9];
  int lane = tid & 63, wv = tid >> 6;
  #pragma unroll
  for (int r = 0; r < 9; ++r) {
    float v = red[r];
    #pragma unroll
    for (int off = 32; off > 0; off >>= 1) v += __shfl_down(v, off, 64);
    if (lane == 0) lred[wv][r] = v;
  }
  __syncthreads();
  if (tid < 9) {
    float s = lred[0][tid] + lred[1][tid] + lred[2][tid] + lred[3][tid];
    if (tid < 8) fnorm[((size_t)(p*KK + tid))*HH + h] = s;
    else         cnorm[row] = s;
  }
}

// K2: merged Gram + fused DP, fp8 substrate, R8 structure.
// Blocks 0..527  : inter 64x64 tiles (upper-tri over 32x32 grid, 528=8*66 XCD-swizzled),
//                  4 waves (2x2 quadrants), BK=64 (64B/row/step), 3-buf depth-2 vmcnt.
// Blocks 528..1039: intra (class p, block jb); same pipeline, 1 gload/wave/step.
// LDS per-row layout: [rows][64B], 8B chunk c at phys c ^ (row&6); staged via
// pre-swizzled global 16B pairs (pair p holds logical pair p ^ ((row&6)>>1)).
__global__ __launch_bounds__(256) void k_gram(const unsigned char* __restrict__ cbf,
    const unsigned char* __restrict__ fbf, const float* __restrict__ cnorm,
    const float* __restrict__ fnorm, float* __restrict__ inter_full,
    float* __restrict__ intra_pk) {
  __shared__ char smem[24576];   // inter: 3 x 8 KB; intra: 3 x 4 KB + epilogue
  int tid = threadIdx.x, lane = tid & 63, w = tid >> 6;
  int ln = lane & 15, kq = lane >> 4;
  int cch = (lane & 3) ^ ((lane >> 3) & 3);   // pre-swizzled 16B pair for staging

  if (blockIdx.x < 528) {
    // ---------------- inter path ----------------
    int bid = (blockIdx.x & 7)*66 + (blockIdx.x >> 3);      // 528 = 8*66, bijective
    int tI = 0, rem = bid;
    while (rem >= 32 - tI) { rem -= 32 - tI; ++tI; }
    int tJ = tI + rem;
    int wr = w >> 1, wc = w & 1;
    f32x4 acc[2][2];
    #pragma unroll
    for (int a = 0; a < 2; ++a)
      #pragma unroll
      for (int b = 0; b < 2; ++b)
        #pragma unroll
        for (int e = 0; e < 4; ++e) acc[a][b][e] = 0.f;

    // staging: wave w stages 16 rows of A and of B (1 gload each)
    const unsigned char* gA0 = cbf + (size_t)(tI*64 + w*16 + (lane >> 2))*DD + cch*16;
    const unsigned char* gB0 = cbf + (size_t)(tJ*64 + w*16 + (lane >> 2))*DD + cch*16;

    // fragment byte offsets: row*64 + ((ks*4+kq)^(row&6))*8, row&6 == ln&6
    int aofs[2][2], bofs[2][2];
    #pragma unroll
    for (int ks = 0; ks < 2; ++ks) {
      int phys = ((ks*4 + kq) ^ (ln & 6))*8;
      #pragma unroll
      for (int mt = 0; mt < 2; ++mt) {
        aofs[ks][mt] = (wr*32 + mt*16 + ln)*64 + phys;
        bofs[ks][mt] = (wc*32 + mt*16 + ln)*64 + phys;
      }
    }

    auto stage = [&](int tt, int bi) {
      int k0 = tt * 64;
      char* A = smem + bi*8192;
      gload_lds16(gA0 + k0, A + w*1024 + lane*16);
      gload_lds16(gB0 + k0, A + 4096 + w*1024 + lane*16);
    };
    auto do_step = [&](int bi) {
      const char* A = smem + bi*8192;
      const char* B = A + 4096;
      #pragma unroll
      for (int ks = 0; ks < 2; ++ks) {
        long long af[2], bf[2];
        #pragma unroll
        for (int mt = 0; mt < 2; ++mt) {
          af[mt] = *(const long long*)(A + aofs[ks][mt]);
          bf[mt] = *(const long long*)(B + bofs[ks][mt]);
        }
        #pragma unroll
        for (int mt = 0; mt < 2; ++mt)
          #pragma unroll
          for (int nt = 0; nt < 2; ++nt)
            acc[mt][nt] = __builtin_amdgcn_mfma_f32_16x16x32_fp8_fp8(af[mt], bf[nt], acc[mt][nt], 0, 0, 0);
      }
    };

    stage(0, 0);
    stage(1, 1);
    asm volatile("s_waitcnt vmcnt(2)" ::: "memory");
    __builtin_amdgcn_s_barrier();
    for (int t = 0; t < 30; ++t) {
      stage(t + 2, (t + 2) % 3);
      do_step(t % 3);
      asm volatile("s_waitcnt vmcnt(2)" ::: "memory");
      __builtin_amdgcn_s_barrier();
    }
    do_step(0);                                           // t=30
    asm volatile("s_waitcnt vmcnt(0)" ::: "memory");
    __builtin_amdgcn_s_barrier();
    do_step(1);                                           // t=31
    __syncthreads();

    // epilogue: tanh -> wave-private LDS tile -> in-wave DP -> inter_full (+mirror)
    int a = tI*2 + wr, b = tJ*2 + wc;
    bool own = (a < b);
    float* tile = (float*)(smem + w*4096);
    if (own) {
      #pragma unroll
      for (int mt = 0; mt < 2; ++mt) {
        #pragma unroll
        for (int nt = 0; nt < 2; ++nt) {
          int j  = nt*16 + ln;
          int cc = tJ*64 + wc*32 + j;
          float nc = cnorm[cc];
          #pragma unroll
          for (int v = 0; v < 4; ++v) {
            int i  = mt*16 + kq*4 + v;
            int rr = tI*64 + wr*32 + i;
            float d2 = cnorm[rr] + nc - 2.f*acc[mt][nt][v];
            tile[(i << 5) + j] = tanhf(0.5f*sqrtf(fmaxf(d2, 1e-12f)));
          }
        }
      }
    }
    __syncthreads();
    if (own) {
      float A = dp_wave(tile, lane & 31, 32);
      if (lane == 31) {
        inter_full[a*64 + b] = A;
        inter_full[b*64 + a] = A;
      }
    }
  } else {
    // ---------------- intra path ----------------
    int bid = (int)blockIdx.x - 528;
    int p = bid >> 3, jb = bid & 7;
    int ks = w >> 1, nt = w & 1;
    f32x4 acc[2];
    #pragma unroll
    for (int mi = 0; mi < 2; ++mi)
      #pragma unroll
      for (int e = 0; e < 4; ++e) acc[mi][e] = 0.f;

    int hw = w & 1;
    const unsigned char* g0 = (w < 2)
        ? cbf + (size_t)(p*32 + hw*16 + (lane >> 2))*DD + cch*16
        : fbf + (size_t)(p*256 + jb*32 + hw*16 + (lane >> 2))*DD + cch*16;
    int isB = (w >= 2);

    int phys = ((ks*4 + kq) ^ (ln & 6))*8;
    int aofs[2];
    #pragma unroll
    for (int mi = 0; mi < 2; ++mi) aofs[mi] = (mi*16 + ln)*64 + phys;
    int bofs = (nt*16 + ln)*64 + phys;

    auto stage = [&](int tt, int bi) {
      int k0 = tt * 64;
      char* S = smem + bi*4096 + isB*2048;
      gload_lds16(g0 + k0, S + hw*1024 + lane*16);
    };
    auto do_step = [&](int bi) {
      const char* A = smem + bi*4096;
      const char* B = A + 2048;
      long long bfr = *(const long long*)(B + bofs);
      #pragma unroll
      for (int mi = 0; mi < 2; ++mi) {
        long long af = *(const long long*)(A + aofs[mi]);
        acc[mi] = __builtin_amdgcn_mfma_f32_16x16x32_fp8_fp8(af, bfr, acc[mi], 0, 0, 0);
      }
    };

    stage(0, 0);
    stage(1, 1);
    asm volatile("s_waitcnt vmcnt(1)" ::: "memory");
    __builtin_amdgcn_s_barrier();
    for (int t = 0; t < 30; ++t) {
      stage(t + 2, (t + 2) % 3);
      do_step(t % 3);
      asm volatile("s_waitcnt vmcnt(1)" ::: "memory");
      __builtin_amdgcn_s_barrier();
    }
    do_step(0);
    asm volatile("s_waitcnt vmcnt(0)" ::: "memory");
    __builtin_amdgcn_s_barrier();
    do_step(1);

    // K-split reduce: waves 2,3 (ks=1) -> waves 0,1 (ks=0), matched nt
    float* fb = (float*)smem;
    float* tile = (float*)(smem + 16384);   // 32x32 pair tile
    __syncthreads();
    if (w >= 2) {
      #pragma unroll
      for (int mi = 0; mi < 2; ++mi)
        *(f32x4*)(fb + ((w - 2)*2 + mi)*256 + lane*4) = acc[mi];
    }
    __syncthreads();
    if (w < 2) {
      #pragma unroll
      for (int mi = 0; mi < 2; ++mi)
        acc[mi] += *(const f32x4*)(fb + (w*2 + mi)*256 + lane*4);
      int cl = jb*32 + nt*16 + ln;
      float nf = fnorm[(size_t)p*256 + cl];
      #pragma unroll
      for (int mi = 0; mi < 2; ++mi) {
        #pragma unroll
        for (int v = 0; v < 4; ++v) {
          int i = mi*16 + kq*4 + v;
          float d2 = cnorm[p*32 + i] + nf - 2.f*acc[mi][v];
          tile[(i << 5) + (nt*16 + ln)] = tanhf(0.5f*sqrtf(fmaxf(d2, 1e-12f)));
        }
      }
    }
    __syncthreads();
    if (w == 0) {
      float A = dp_wave(tile, lane & 31, 32);
      if (lane == 31) intra_pk[p*8 + jb] = A;
    }
  }
}

// K3: reductions + loss. out = [loss, intra_max[64], inter_min[64]]
__global__ __launch_bounds__(64) void k_final(const float* __restrict__ inter_full,
    const float* __restrict__ intra_pk, float* __restrict__ out) {
  int p = threadIdx.x;
  const float INF = __builtin_inff();
  float mn = INF;
  #pragma unroll 8
  for (int b = 0; b < 64; ++b)
    if (b != p) mn = fminf(mn, inter_full[p*64 + b]);
  float mx = -INF;
  #pragma unroll
  for (int k = 0; k < 8; ++k) mx = fmaxf(mx, intra_pk[p*8 + k]);
  out[1 + p]  = mx;
  out[65 + p] = mn;
  float v = fmaxf(mx - mn + 10.0f, 0.0f);
  #pragma unroll
  for (int off = 32; off > 0; off >>= 1) v += __shfl_down(v, off, 64);
  if (p == 0) out[0] = v * (1.0f/64.0f);
}

extern "C" void kernel_launch(void* const* d_in, const int* in_sizes, int n_in,
                              void* d_out, int out_size, void* d_ws, size_t ws_size,
                              hipStream_t stream) {
  const float* feat = (const float*)d_in[0];
  float* out = (float*)d_out;
  char* w = (char*)d_ws;
  // workspace layout (bytes)
  unsigned char* cbf  = (unsigned char*)w;                  // 2048*2048   = 4,194,304
  unsigned char* fbf  = (unsigned char*)(w + 4194304);      // 16384*2048  = 33,554,432
  float* cnorm        = (float*)(w + 37748736);             // 8,192
  float* fnorm        = (float*)(w + 37756928);             // 65,536
  float* inter_full   = (float*)(w + 37822464);             // 16,384
  float* intra_pk     = (float*)(w + 37838848);             // 2,048
  // total ~37.8 MB

  k_centers<<<RR, 256, 0, stream>>>(feat, cbf, fbf, cnorm, fnorm);
  k_gram<<<1040, 256, 0, stream>>>(cbf, fbf, cnorm, fnorm, inter_full, intra_pk);
  k_final<<<1, 64, 0, stream>>>(inter_full, intra_pk, out);
}